// Round 13
// baseline (258.123 us; speedup 1.0000x reference)
//
#include <hip/hip_runtime.h>
#include <hip/hip_bf16.h>
#include <hip/hip_fp16.h>

constexpr int IN_DIM = 128;
constexpr int HID    = 256;

typedef _Float16 f16x8 __attribute__((ext_vector_type(8)));
typedef float    f32x4 __attribute__((ext_vector_type(4)));

// ---------------- setup kernels ----------------

__global__ void zero_int2(int* __restrict__ a, int* __restrict__ b, int n) {
    int i = blockIdx.x * blockDim.x + threadIdx.x;
    if (i < n) { a[i] = 0; b[i] = 0; }
}

__global__ void count_deg(const int* __restrict__ dst, int* __restrict__ deg, int e) {
    int i = blockIdx.x * blockDim.x + threadIdx.x;
    if (i < e) atomicAdd(&deg[dst[i]], 1);
}

// ---- scan phase 1: per-block scan + block total; also emits dinv ----
__global__ __launch_bounds__(256) void scan_partial(const int* __restrict__ deg,
                                                    int* __restrict__ escan,
                                                    int* __restrict__ blocksum,
                                                    float* __restrict__ dinv, int n) {
    __shared__ int lds[256];
    int t = threadIdx.x;
    int i = blockIdx.x * 256 + t;
    int v = (i < n) ? deg[i] : 0;
    if (i < n) dinv[i] = rsqrtf((float)v + 1.0f);
    lds[t] = v;
    __syncthreads();
    for (int off = 1; off < 256; off <<= 1) {
        int a = lds[t];
        int w = (t >= off) ? lds[t - off] : 0;
        __syncthreads();
        lds[t] = a + w;
        __syncthreads();
    }
    if (i < n) escan[i] = lds[t] - v;
    if (t == 255) blocksum[blockIdx.x] = lds[255];
}

// ---- scan phases 2+3 fused ----
__global__ __launch_bounds__(256) void scan_rest(const int* __restrict__ escan,
                                                 const int* __restrict__ blocksum,
                                                 int nb, int* __restrict__ rowptr, int n) {
    __shared__ int lds[256];
    int t = threadIdx.x;
    int v = (t < nb) ? blocksum[t] : 0;
    lds[t] = v;
    __syncthreads();
    for (int off = 1; off < 256; off <<= 1) {
        int a = lds[t];
        int w = (t >= off) ? lds[t - off] : 0;
        __syncthreads();
        lds[t] = a + w;
        __syncthreads();
    }
    int boff = (blockIdx.x > 0) ? lds[blockIdx.x - 1] : 0;
    int i = blockIdx.x * 256 + t;
    if (i < n) rowptr[i] = escan[i] + boff;
    if (blockIdx.x == 0 && t == 0) rowptr[n] = lds[nb - 1];
}

__global__ void scatter_edges(const int* __restrict__ src, const int* __restrict__ dst,
                              const int* __restrict__ rowptr, int* __restrict__ cursor,
                              const float* __restrict__ dinv,
                              int* __restrict__ ssrc, float* __restrict__ ewt, int e) {
    int i = blockIdx.x * blockDim.x + threadIdx.x;
    if (i < e) {
        int d = dst[i];
        int s = src[i];
        int p = atomicAdd(&cursor[d], 1);
        int idx = rowptr[d] + p;
        ssrc[idx] = s;
        ewt[idx]  = dinv[s] * dinv[d];
    }
}

// ---- fused input conversion: W1 -> B1 panel, W2 -> B2 panel, x -> fp16 ----
__device__ inline void conv_B_elem(const float* B, ushort* Bp, int id, int /*K*/) {
    int k  = id >> 6;
    int n4 = (id & 63) * 4;
    float4 v = *(const float4*)(B + (size_t)k * 256 + n4);
    size_t base = (size_t)(k >> 5) * (256 * 32) + (k & 31);
    Bp[base + (size_t)(n4 + 0) * 32] = __half_as_ushort(__float2half(v.x));
    Bp[base + (size_t)(n4 + 1) * 32] = __half_as_ushort(__float2half(v.y));
    Bp[base + (size_t)(n4 + 2) * 32] = __half_as_ushort(__float2half(v.z));
    Bp[base + (size_t)(n4 + 3) * 32] = __half_as_ushort(__float2half(v.w));
}

__global__ void convert_inputs(const float* __restrict__ W1, ushort* __restrict__ B1p,
                               const float* __restrict__ W2, ushort* __restrict__ B2p,
                               const float* __restrict__ x, ushort* __restrict__ xh,
                               int total4) {
    int id = blockIdx.x * 256 + threadIdx.x;
    if (id < IN_DIM * 64) {
        conv_B_elem(W1, B1p, id, IN_DIM);
    } else if (id < IN_DIM * 64 + HID * 64) {
        conv_B_elem(W2, B2p, id - IN_DIM * 64, HID);
    } else {
        int i = id - (IN_DIM * 64 + HID * 64);
        if (i < total4) {
            float4 v = *(const float4*)(x + (size_t)i * 4);
            ushort4 o;
            o.x = __half_as_ushort(__float2half(v.x));
            o.y = __half_as_ushort(__float2half(v.y));
            o.z = __half_as_ushort(__float2half(v.z));
            o.w = __half_as_ushort(__float2half(v.w));
            *(ushort4*)(xh + (size_t)i * 4) = o;
        }
    }
}

// ---------------- aggregation: one wave per node, fp16 gather, 16-deep MLP -
// fp32 accum; writes result as fp16 panel in MFMA layout [k>>5][row][k&31],
// chunk stride Mp*32. Inner loop batches 16 independent row loads before any
// use (R12: 8-deep gave 54->46 µs; still 2x above the 23 µs HBM floor).
template <int K>  // K halves per row: 128 or 256
__global__ __launch_bounds__(256) void aggregate_p(const ushort* __restrict__ h,
                                                   const int* __restrict__ rowptr,
                                                   const int* __restrict__ ssrc,
                                                   const float* __restrict__ ewt,
                                                   const float* __restrict__ dinv,
                                                   ushort* __restrict__ Pp,
                                                   int n, int Mp) {
    constexpr int VH = K / 64;  // halves per lane: 2 or 4
    int wid  = (blockIdx.x * 256 + threadIdx.x) >> 6;
    int lane = threadIdx.x & 63;
    if (wid >= n) return;
    float di = dinv[wid];
    float sw = di * di;
    float acc[VH];
    {
        const ushort* row = h + (size_t)wid * K + lane * VH;
        if constexpr (VH == 4) {
            uint2 u = *(const uint2*)row;
            float2 fa = __half22float2(*(__half2*)&u.x);
            float2 fb = __half22float2(*(__half2*)&u.y);
            acc[0] = fa.x * sw; acc[1] = fa.y * sw; acc[2] = fb.x * sw; acc[3] = fb.y * sw;
        } else {
            uint u = *(const uint*)row;
            float2 fa = __half22float2(*(__half2*)&u);
            acc[0] = fa.x * sw; acc[1] = fa.y * sw;
        }
    }
    int beg = rowptr[wid], fin = rowptr[wid + 1];
    for (int b = beg; b < fin; b += 64) {
        int cnt = fin - b;
        if (cnt > 64) cnt = 64;
        int   sv = (lane < cnt) ? ssrc[b + lane] : 0;
        float wv = (lane < cnt) ? ewt[b + lane]  : 0.f;
        int t = 0;
        // 16-wide: all loads issued before any use -> 16 outstanding per wave
        for (; t + 16 <= cnt; t += 16) {
            float wr[16];
            if constexpr (VH == 4) {
                uint2 u[16];
#pragma unroll
                for (int k = 0; k < 16; k++) {
                    int s = __shfl(sv, t + k);
                    wr[k] = __shfl(wv, t + k);
                    u[k] = *(const uint2*)(h + (size_t)s * K + lane * VH);
                }
#pragma unroll
                for (int k = 0; k < 16; k++) {
                    float2 fa = __half22float2(*(__half2*)&u[k].x);
                    float2 fb = __half22float2(*(__half2*)&u[k].y);
                    acc[0] += fa.x * wr[k]; acc[1] += fa.y * wr[k];
                    acc[2] += fb.x * wr[k]; acc[3] += fb.y * wr[k];
                }
            } else {
                uint u[16];
#pragma unroll
                for (int k = 0; k < 16; k++) {
                    int s = __shfl(sv, t + k);
                    wr[k] = __shfl(wv, t + k);
                    u[k] = *(const uint*)(h + (size_t)s * K + lane * VH);
                }
#pragma unroll
                for (int k = 0; k < 16; k++) {
                    float2 fa = __half22float2(*(__half2*)&u[k]);
                    acc[0] += fa.x * wr[k]; acc[1] += fa.y * wr[k];
                }
            }
        }
        // 8-wide
        for (; t + 8 <= cnt; t += 8) {
            float wr[8];
            if constexpr (VH == 4) {
                uint2 u[8];
#pragma unroll
                for (int k = 0; k < 8; k++) {
                    int s = __shfl(sv, t + k);
                    wr[k] = __shfl(wv, t + k);
                    u[k] = *(const uint2*)(h + (size_t)s * K + lane * VH);
                }
#pragma unroll
                for (int k = 0; k < 8; k++) {
                    float2 fa = __half22float2(*(__half2*)&u[k].x);
                    float2 fb = __half22float2(*(__half2*)&u[k].y);
                    acc[0] += fa.x * wr[k]; acc[1] += fa.y * wr[k];
                    acc[2] += fb.x * wr[k]; acc[3] += fb.y * wr[k];
                }
            } else {
                uint u[8];
#pragma unroll
                for (int k = 0; k < 8; k++) {
                    int s = __shfl(sv, t + k);
                    wr[k] = __shfl(wv, t + k);
                    u[k] = *(const uint*)(h + (size_t)s * K + lane * VH);
                }
#pragma unroll
                for (int k = 0; k < 8; k++) {
                    float2 fa = __half22float2(*(__half2*)&u[k]);
                    acc[0] += fa.x * wr[k]; acc[1] += fa.y * wr[k];
                }
            }
        }
        // 4-wide tail
        for (; t + 4 <= cnt; t += 4) {
            float wr[4];
            if constexpr (VH == 4) {
                uint2 u[4];
#pragma unroll
                for (int k = 0; k < 4; k++) {
                    int s = __shfl(sv, t + k);
                    wr[k] = __shfl(wv, t + k);
                    u[k] = *(const uint2*)(h + (size_t)s * K + lane * VH);
                }
#pragma unroll
                for (int k = 0; k < 4; k++) {
                    float2 fa = __half22float2(*(__half2*)&u[k].x);
                    float2 fb = __half22float2(*(__half2*)&u[k].y);
                    acc[0] += fa.x * wr[k]; acc[1] += fa.y * wr[k];
                    acc[2] += fb.x * wr[k]; acc[3] += fb.y * wr[k];
                }
            } else {
                uint u[4];
#pragma unroll
                for (int k = 0; k < 4; k++) {
                    int s = __shfl(sv, t + k);
                    wr[k] = __shfl(wv, t + k);
                    u[k] = *(const uint*)(h + (size_t)s * K + lane * VH);
                }
#pragma unroll
                for (int k = 0; k < 4; k++) {
                    float2 fa = __half22float2(*(__half2*)&u[k]);
                    acc[0] += fa.x * wr[k]; acc[1] += fa.y * wr[k];
                }
            }
        }
        // scalar tail
        for (; t < cnt; t++) {
            int   s = __shfl(sv, t);
            float w = __shfl(wv, t);
            const ushort* r = h + (size_t)s * K + lane * VH;
            if constexpr (VH == 4) {
                uint2 u = *(const uint2*)r;
                float2 fa = __half22float2(*(__half2*)&u.x);
                float2 fb = __half22float2(*(__half2*)&u.y);
                acc[0] += fa.x * w; acc[1] += fa.y * w;
                acc[2] += fb.x * w; acc[3] += fb.y * w;
            } else {
                uint u = *(const uint*)r;
                float2 fa = __half22float2(*(__half2*)&u);
                acc[0] += fa.x * w; acc[1] += fa.y * w;
            }
        }
    }
    int kglob = lane * VH;
    int chunk = kglob >> 5;
    int inner = kglob & 31;
    size_t base = (size_t)chunk * Mp * 32 + (size_t)wid * 32 + inner;
    if constexpr (VH == 4) {
        __half2 p0 = __floats2half2_rn(acc[0], acc[1]);
        __half2 p1 = __floats2half2_rn(acc[2], acc[3]);
        *(uint2*)&Pp[base] = make_uint2(*(uint*)&p0, *(uint*)&p1);
    } else {
        __half2 p0 = __floats2half2_rn(acc[0], acc[1]);
        *(uint*)&Pp[base] = *(uint*)&p0;
    }
}

// ---------------- fp16 MFMA GEMM, BM=32, B prefetch distance 2 -------------
// A panel [K/32][Mp][32] fp16: block DMAs its 32-row A tile to LDS up front,
// one barrier, then barrier-free K-loop (A via ds_read_b128, B from L2,
// 3-slot rotation = 2 chunks of prefetch distance).
// MODE 1: C16[M,256] = fp16(relu(A@B + bias))
// MODE 2: out[M,2]  = relu(A@B + bias) @ Wl + bl
template <int K, int MODE>
__global__ __launch_bounds__(256, 4) void gemm_f16(const ushort* __restrict__ Ap,
                                                   const ushort* __restrict__ Bp,
                                                   const float* __restrict__ bias,
                                                   ushort* __restrict__ C16,
                                                   const float* __restrict__ Wl,
                                                   const float* __restrict__ bl,
                                                   float* __restrict__ out,
                                                   int M, int Mp) {
    constexpr int NC = K / 32;
    __shared__ ushort Asm[NC * 1024];
    __shared__ float part[4][32][2];

    int tid  = threadIdx.x;
    int w    = tid >> 6;
    int lane = tid & 63;
    int l15  = lane & 15;
    int quad = lane >> 4;
    int row0 = blockIdx.x * 32;

    constexpr int TOT = NC * 2;
    for (int j = w; j < TOT; j += 4) {
        int c   = j >> 1;
        int sub = j & 1;
        const ushort* g = Ap + (size_t)c * Mp * 32 + (size_t)(row0 + sub * 16) * 32;
        ushort* l = Asm + c * 1024 + sub * 512;
        __builtin_amdgcn_global_load_lds(
            (const __attribute__((address_space(1))) uint*)(g + (size_t)lane * 8),
            (__attribute__((address_space(3))) uint*)l, 16, 0, 0);
    }
    __syncthreads();

    size_t bco[4];
#pragma unroll
    for (int j = 0; j < 4; j++) bco[j] = (size_t)(w * 64 + j * 16 + l15) * 32 + quad * 8;

    f16x8 fb[3][4];
    auto loadB = [&](int c, int buf) {
        const ushort* bp = Bp + (size_t)c * 256 * 32;
#pragma unroll
        for (int j = 0; j < 4; j++) fb[buf][j] = *(const f16x8*)(bp + bco[j]);
    };

    f32x4 acc[2][4] = {};
    loadB(0, 0);
    if constexpr (NC > 1) loadB(1, 1);
#pragma unroll
    for (int c = 0; c < NC; c++) {
        int cur = c % 3;
        if (c + 2 < NC) loadB(c + 2, (c + 2) % 3);
        f16x8 fa[2];
#pragma unroll
        for (int i = 0; i < 2; i++) {
            int off = c * 1024 + (i * 16 + l15) * 32 + quad * 8;
            fa[i] = *(const f16x8*)&Asm[off];
        }
#pragma unroll
        for (int i = 0; i < 2; i++)
#pragma unroll
            for (int j = 0; j < 4; j++)
                acc[i][j] = __builtin_amdgcn_mfma_f32_16x16x32_f16(fa[i], fb[cur][j], acc[i][j], 0, 0, 0);
    }

    float bj[4];
#pragma unroll
    for (int j = 0; j < 4; j++) bj[j] = bias[w * 64 + j * 16 + l15];

    if constexpr (MODE == 1) {
#pragma unroll
        for (int i = 0; i < 2; i++)
#pragma unroll
            for (int reg = 0; reg < 4; reg++) {
                int r = row0 + i * 16 + quad * 4 + reg;
                if (r < M) {
                    ushort* cp = C16 + (size_t)r * 256 + w * 64 + l15;
#pragma unroll
                    for (int j = 0; j < 4; j++) {
                        float v = fmaxf(acc[i][j][reg] + bj[j], 0.f);
                        cp[j * 16] = __half_as_ushort(__float2half(v));
                    }
                }
            }
    } else {
        float wl0[4], wl1[4];
#pragma unroll
        for (int j = 0; j < 4; j++) {
            int cj = w * 64 + j * 16 + l15;
            float2 wv = *(const float2*)(Wl + cj * 2);
            wl0[j] = wv.x; wl1[j] = wv.y;
        }
#pragma unroll
        for (int i = 0; i < 2; i++)
#pragma unroll
            for (int reg = 0; reg < 4; reg++) {
                float s0 = 0.f, s1 = 0.f;
#pragma unroll
                for (int j = 0; j < 4; j++) {
                    float v = fmaxf(acc[i][j][reg] + bj[j], 0.f);
                    s0 += v * wl0[j];
                    s1 += v * wl1[j];
                }
#pragma unroll
                for (int off = 1; off < 16; off <<= 1) {
                    s0 += __shfl_xor(s0, off);
                    s1 += __shfl_xor(s1, off);
                }
                if (l15 == 0) {
                    int r = i * 16 + quad * 4 + reg;
                    part[w][r][0] = s0;
                    part[w][r][1] = s1;
                }
            }
        __syncthreads();
        if (tid < 64) {
            int r = tid >> 1, o = tid & 1;
            int grr = row0 + r;
            if (grr < M) {
                float s = part[0][r][o] + part[1][r][o] + part[2][r][o] + part[3][r][o] + bl[o];
                out[(size_t)grr * 2 + o] = s;
            }
        }
    }
}

// ---------------- launch ----------------

extern "C" void kernel_launch(void* const* d_in, const int* in_sizes, int n_in,
                              void* d_out, int out_size, void* d_ws, size_t ws_size,
                              hipStream_t stream) {
    const float* x  = (const float*)d_in[0];
    const int*   ei = (const int*)d_in[1];
    const float* W1 = (const float*)d_in[2];
    const float* b1 = (const float*)d_in[3];
    const float* W2 = (const float*)d_in[4];
    const float* b2 = (const float*)d_in[5];
    const float* Wl = (const float*)d_in[6];
    const float* bl = (const float*)d_in[7];
    float* out = (float*)d_out;

    int n = in_sizes[0] / IN_DIM;  // 50000
    int e = in_sizes[1] / 2;       // 600000
    const int* src = ei;
    const int* dst = ei + e;

    int gblocks = (n + 31) / 32;   // BM=32
    int Mp = gblocks * 32;

    char* ws = (char*)d_ws;
    size_t off = 0;
    auto alloc = [&](size_t bytes) -> void* {
        void* p = ws + off;
        off += (bytes + 255) & ~(size_t)255;
        return p;
    };
    int*    deg    = (int*)alloc((size_t)n * 4);
    int*    cursor = (int*)alloc((size_t)n * 4);
    float*  dinv   = (float*)alloc((size_t)n * 4);
    int*    rowptr = (int*)alloc((size_t)(n + 1) * 4);
    int*    escan  = (int*)alloc((size_t)n * 4);
    int*    bsum   = (int*)alloc(256 * 4);
    int*    ssrc   = (int*)alloc((size_t)e * 4);
    float*  ewt    = (float*)alloc((size_t)e * 4);
    ushort* xh     = (ushort*)alloc((size_t)n * IN_DIM * 2);
    ushort* h1     = (ushort*)alloc((size_t)n * HID * 2);
    ushort* A1p    = (ushort*)alloc((size_t)Mp * IN_DIM * 2);
    ushort* A2p    = (ushort*)alloc((size_t)Mp * HID * 2);
    ushort* B1p    = (ushort*)alloc((size_t)IN_DIM * 256 * 2);
    ushort* B2p    = (ushort*)alloc((size_t)HID * 256 * 2);

    int nb = (n + 255) / 256;   // 196 (<= 256 required by scan_rest)
    int eb = (e + 255) / 256;

    zero_int2<<<nb, 256, 0, stream>>>(deg, cursor, n);
    count_deg<<<eb, 256, 0, stream>>>(dst, deg, e);

    scan_partial<<<nb, 256, 0, stream>>>(deg, escan, bsum, dinv, n);
    scan_rest<<<nb, 256, 0, stream>>>(escan, bsum, nb, rowptr, n);

    scatter_edges<<<eb, 256, 0, stream>>>(src, dst, rowptr, cursor, dinv, ssrc, ewt, e);

    int total4 = n * IN_DIM / 4;
    int cblocks = (IN_DIM * 64 + HID * 64 + total4 + 255) / 256;
    convert_inputs<<<cblocks, 256, 0, stream>>>(W1, B1p, W2, B2p, x, xh, total4);

    // layer 1: aggregate fp16 x -> A1 panel, fp16-MFMA GEMM -> fp16 h1
    aggregate_p<IN_DIM><<<(n + 3) / 4, 256, 0, stream>>>(xh, rowptr, ssrc, ewt, dinv,
                                                         A1p, n, Mp);
    gemm_f16<IN_DIM, 1><<<gblocks, 256, 0, stream>>>(A1p, B1p, b1, h1,
                                                     nullptr, nullptr, nullptr, n, Mp);

    // layer 2: aggregate fp16 h1 -> A2 panel, fp16-MFMA GEMM + final projection
    aggregate_p<HID><<<(n + 3) / 4, 256, 0, stream>>>(h1, rowptr, ssrc, ewt, dinv,
                                                      A2p, n, Mp);
    gemm_f16<HID, 2><<<gblocks, 256, 0, stream>>>(A2p, B2p, b2, nullptr,
                                                  Wl, bl, out, n, Mp);
}

// Round 14
// 254.840 us; speedup vs baseline: 1.0129x; 1.0129x over previous
//
#include <hip/hip_runtime.h>
#include <hip/hip_bf16.h>
#include <hip/hip_fp16.h>

constexpr int IN_DIM = 128;
constexpr int HID    = 256;

typedef _Float16 f16x8 __attribute__((ext_vector_type(8)));
typedef float    f32x4 __attribute__((ext_vector_type(4)));

// ---------------- setup kernels ----------------

__global__ void count_deg(const int* __restrict__ dst, int* __restrict__ deg, int e) {
    int i = blockIdx.x * blockDim.x + threadIdx.x;
    if (i < e) atomicAdd(&deg[dst[i]], 1);
}

// ---- scan phase 1: per-block scan + block total; also emits dinv ----
__global__ __launch_bounds__(256) void scan_partial(const int* __restrict__ deg,
                                                    int* __restrict__ escan,
                                                    int* __restrict__ blocksum,
                                                    float* __restrict__ dinv, int n) {
    __shared__ int lds[256];
    int t = threadIdx.x;
    int i = blockIdx.x * 256 + t;
    int v = (i < n) ? deg[i] : 0;
    if (i < n) dinv[i] = rsqrtf((float)v + 1.0f);
    lds[t] = v;
    __syncthreads();
    for (int off = 1; off < 256; off <<= 1) {
        int a = lds[t];
        int w = (t >= off) ? lds[t - off] : 0;
        __syncthreads();
        lds[t] = a + w;
        __syncthreads();
    }
    if (i < n) escan[i] = lds[t] - v;
    if (t == 255) blocksum[blockIdx.x] = lds[255];
}

// ---- scan phases 2+3 fused ----
__global__ __launch_bounds__(256) void scan_rest(const int* __restrict__ escan,
                                                 const int* __restrict__ blocksum,
                                                 int nb, int* __restrict__ rowptr, int n) {
    __shared__ int lds[256];
    int t = threadIdx.x;
    int v = (t < nb) ? blocksum[t] : 0;
    lds[t] = v;
    __syncthreads();
    for (int off = 1; off < 256; off <<= 1) {
        int a = lds[t];
        int w = (t >= off) ? lds[t - off] : 0;
        __syncthreads();
        lds[t] = a + w;
        __syncthreads();
    }
    int boff = (blockIdx.x > 0) ? lds[blockIdx.x - 1] : 0;
    int i = blockIdx.x * 256 + t;
    if (i < n) rowptr[i] = escan[i] + boff;
    if (blockIdx.x == 0 && t == 0) rowptr[n] = lds[nb - 1];
}

__global__ void scatter_edges(const int* __restrict__ src, const int* __restrict__ dst,
                              const int* __restrict__ rowptr, int* __restrict__ cursor,
                              const float* __restrict__ dinv,
                              int* __restrict__ ssrc, float* __restrict__ ewt, int e) {
    int i = blockIdx.x * blockDim.x + threadIdx.x;
    if (i < e) {
        int d = dst[i];
        int s = src[i];
        int p = atomicAdd(&cursor[d], 1);
        int idx = rowptr[d] + p;
        ssrc[idx] = s;
        ewt[idx]  = dinv[s] * dinv[d];
    }
}

// ---- fused: W1/W2 -> fp16 panels, x -> fp16, zero deg+cursor (R13: -1 launch)
__device__ inline void conv_B_elem(const float* B, ushort* Bp, int id) {
    int k  = id >> 6;
    int n4 = (id & 63) * 4;
    float4 v = *(const float4*)(B + (size_t)k * 256 + n4);
    size_t base = (size_t)(k >> 5) * (256 * 32) + (k & 31);
    Bp[base + (size_t)(n4 + 0) * 32] = __half_as_ushort(__float2half(v.x));
    Bp[base + (size_t)(n4 + 1) * 32] = __half_as_ushort(__float2half(v.y));
    Bp[base + (size_t)(n4 + 2) * 32] = __half_as_ushort(__float2half(v.z));
    Bp[base + (size_t)(n4 + 3) * 32] = __half_as_ushort(__float2half(v.w));
}

__global__ void convert_inputs(const float* __restrict__ W1, ushort* __restrict__ B1p,
                               const float* __restrict__ W2, ushort* __restrict__ B2p,
                               const float* __restrict__ x, ushort* __restrict__ xh,
                               int total4, int* __restrict__ deg,
                               int* __restrict__ cursor, int n) {
    int id = blockIdx.x * 256 + threadIdx.x;
    constexpr int C1 = IN_DIM * 64;
    constexpr int C2 = C1 + HID * 64;
    if (id < C1) {
        conv_B_elem(W1, B1p, id);
    } else if (id < C2) {
        conv_B_elem(W2, B2p, id - C1);
    } else if (id < C2 + total4) {
        int i = id - C2;
        float4 v = *(const float4*)(x + (size_t)i * 4);
        ushort4 o;
        o.x = __half_as_ushort(__float2half(v.x));
        o.y = __half_as_ushort(__float2half(v.y));
        o.z = __half_as_ushort(__float2half(v.z));
        o.w = __half_as_ushort(__float2half(v.w));
        *(ushort4*)(xh + (size_t)i * 4) = o;
    } else {
        int i = id - (C2 + total4);
        if (i < n) { deg[i] = 0; cursor[i] = 0; }
    }
}

// ---------------- aggregation: one wave per node, fp16 gather, 8-deep MLP --
// (R13: reverted 16-deep — compiler wouldn't hold 16 in flight; 8-deep is the
// measured optimum, fabric-serving-rate bound at ~46 µs for K=256.)
template <int K>  // K halves per row: 128 or 256
__global__ __launch_bounds__(256) void aggregate_p(const ushort* __restrict__ h,
                                                   const int* __restrict__ rowptr,
                                                   const int* __restrict__ ssrc,
                                                   const float* __restrict__ ewt,
                                                   const float* __restrict__ dinv,
                                                   ushort* __restrict__ Pp,
                                                   int n, int Mp) {
    constexpr int VH = K / 64;  // halves per lane: 2 or 4
    int wid  = (blockIdx.x * 256 + threadIdx.x) >> 6;
    int lane = threadIdx.x & 63;
    if (wid >= n) return;
    float di = dinv[wid];
    float sw = di * di;
    float acc[VH];
    {
        const ushort* row = h + (size_t)wid * K + lane * VH;
        if constexpr (VH == 4) {
            uint2 u = *(const uint2*)row;
            float2 fa = __half22float2(*(__half2*)&u.x);
            float2 fb = __half22float2(*(__half2*)&u.y);
            acc[0] = fa.x * sw; acc[1] = fa.y * sw; acc[2] = fb.x * sw; acc[3] = fb.y * sw;
        } else {
            uint u = *(const uint*)row;
            float2 fa = __half22float2(*(__half2*)&u);
            acc[0] = fa.x * sw; acc[1] = fa.y * sw;
        }
    }
    int beg = rowptr[wid], fin = rowptr[wid + 1];
    for (int b = beg; b < fin; b += 64) {
        int cnt = fin - b;
        if (cnt > 64) cnt = 64;
        int   sv = (lane < cnt) ? ssrc[b + lane] : 0;
        float wv = (lane < cnt) ? ewt[b + lane]  : 0.f;
        int t = 0;
        for (; t + 8 <= cnt; t += 8) {
            float wr[8];
            if constexpr (VH == 4) {
                uint2 u[8];
#pragma unroll
                for (int k = 0; k < 8; k++) {
                    int s = __shfl(sv, t + k);
                    wr[k] = __shfl(wv, t + k);
                    u[k] = *(const uint2*)(h + (size_t)s * K + lane * VH);
                }
#pragma unroll
                for (int k = 0; k < 8; k++) {
                    float2 fa = __half22float2(*(__half2*)&u[k].x);
                    float2 fb = __half22float2(*(__half2*)&u[k].y);
                    acc[0] += fa.x * wr[k]; acc[1] += fa.y * wr[k];
                    acc[2] += fb.x * wr[k]; acc[3] += fb.y * wr[k];
                }
            } else {
                uint u[8];
#pragma unroll
                for (int k = 0; k < 8; k++) {
                    int s = __shfl(sv, t + k);
                    wr[k] = __shfl(wv, t + k);
                    u[k] = *(const uint*)(h + (size_t)s * K + lane * VH);
                }
#pragma unroll
                for (int k = 0; k < 8; k++) {
                    float2 fa = __half22float2(*(__half2*)&u[k]);
                    acc[0] += fa.x * wr[k]; acc[1] += fa.y * wr[k];
                }
            }
        }
        for (; t + 4 <= cnt; t += 4) {
            float wr[4];
            if constexpr (VH == 4) {
                uint2 u[4];
#pragma unroll
                for (int k = 0; k < 4; k++) {
                    int s = __shfl(sv, t + k);
                    wr[k] = __shfl(wv, t + k);
                    u[k] = *(const uint2*)(h + (size_t)s * K + lane * VH);
                }
#pragma unroll
                for (int k = 0; k < 4; k++) {
                    float2 fa = __half22float2(*(__half2*)&u[k].x);
                    float2 fb = __half22float2(*(__half2*)&u[k].y);
                    acc[0] += fa.x * wr[k]; acc[1] += fa.y * wr[k];
                    acc[2] += fb.x * wr[k]; acc[3] += fb.y * wr[k];
                }
            } else {
                uint u[4];
#pragma unroll
                for (int k = 0; k < 4; k++) {
                    int s = __shfl(sv, t + k);
                    wr[k] = __shfl(wv, t + k);
                    u[k] = *(const uint*)(h + (size_t)s * K + lane * VH);
                }
#pragma unroll
                for (int k = 0; k < 4; k++) {
                    float2 fa = __half22float2(*(__half2*)&u[k]);
                    acc[0] += fa.x * wr[k]; acc[1] += fa.y * wr[k];
                }
            }
        }
        for (; t < cnt; t++) {
            int   s = __shfl(sv, t);
            float w = __shfl(wv, t);
            const ushort* r = h + (size_t)s * K + lane * VH;
            if constexpr (VH == 4) {
                uint2 u = *(const uint2*)r;
                float2 fa = __half22float2(*(__half2*)&u.x);
                float2 fb = __half22float2(*(__half2*)&u.y);
                acc[0] += fa.x * w; acc[1] += fa.y * w;
                acc[2] += fb.x * w; acc[3] += fb.y * w;
            } else {
                uint u = *(const uint*)r;
                float2 fa = __half22float2(*(__half2*)&u);
                acc[0] += fa.x * w; acc[1] += fa.y * w;
            }
        }
    }
    int kglob = lane * VH;
    int chunk = kglob >> 5;
    int inner = kglob & 31;
    size_t base = (size_t)chunk * Mp * 32 + (size_t)wid * 32 + inner;
    if constexpr (VH == 4) {
        __half2 p0 = __floats2half2_rn(acc[0], acc[1]);
        __half2 p1 = __floats2half2_rn(acc[2], acc[3]);
        *(uint2*)&Pp[base] = make_uint2(*(uint*)&p0, *(uint*)&p1);
    } else {
        __half2 p0 = __floats2half2_rn(acc[0], acc[1]);
        *(uint*)&Pp[base] = *(uint*)&p0;
    }
}

// ---------------- fp16 MFMA GEMM: A + B both via LDS-DMA (m97-style) -------
// R13: B register-prefetch was being sunk by the compiler (R7/R8 evidence:
// VGPR collapse). global_load_lds has no VGPR result -> cannot be sunk.
// Per iter: barrier (drains chunk c's B-DMA) -> issue DMA of B chunk c+1 into
// alternate 16 KB LDS buffer -> ds_read+MFMA chunk c. A tile DMA'd whole in
// prologue. LDS 41/49 KB -> 3 blocks/CU, barrier stalls overlap across blocks.
// MODE 1: C16[M,256] = fp16(relu(A@B + bias))
// MODE 2: out[M,2]  = relu(A@B + bias) @ Wl + bl
template <int K, int MODE>
__global__ __launch_bounds__(256, 3) void gemm_f16(const ushort* __restrict__ Ap,
                                                   const ushort* __restrict__ Bp,
                                                   const float* __restrict__ bias,
                                                   ushort* __restrict__ C16,
                                                   const float* __restrict__ Wl,
                                                   const float* __restrict__ bl,
                                                   float* __restrict__ out,
                                                   int M, int Mp) {
    constexpr int NC = K / 32;
    __shared__ ushort Asm[NC * 1024];   // A tile [chunk][row 0..31][32]
    __shared__ ushort Bsm[2][8192];     // B chunk dbuf [n 0..255][32] (16 KB each)
    __shared__ float part[4][32][2];    // MODE 2 only

    int tid  = threadIdx.x;
    int w    = tid >> 6;
    int lane = tid & 63;
    int l15  = lane & 15;
    int quad = lane >> 4;
    int row0 = blockIdx.x * 32;

    // prologue: DMA whole A tile + B chunk 0
    constexpr int TOTA = NC * 2;
    for (int j = w; j < TOTA; j += 4) {
        int c   = j >> 1;
        int sub = j & 1;
        const ushort* g = Ap + (size_t)c * Mp * 32 + (size_t)(row0 + sub * 16) * 32;
        ushort* l = Asm + c * 1024 + sub * 512;
        __builtin_amdgcn_global_load_lds(
            (const __attribute__((address_space(1))) uint*)(g + (size_t)lane * 8),
            (__attribute__((address_space(3))) uint*)l, 16, 0, 0);
    }
#pragma unroll
    for (int j = 0; j < 4; j++) {   // 4 insts/wave x 4 waves = 16 x 1 KB = 16 KB
        int seg = w * 4 + j;
        const ushort* g = Bp + (size_t)seg * 512;
        ushort* l = Bsm[0] + seg * 512;
        __builtin_amdgcn_global_load_lds(
            (const __attribute__((address_space(1))) uint*)(g + (size_t)lane * 8),
            (__attribute__((address_space(3))) uint*)l, 16, 0, 0);
    }

    f32x4 acc[2][4] = {};
#pragma unroll
    for (int c = 0; c < NC; c++) {
        __syncthreads();  // drains DMA of chunk c (and A on first iter); WAR-safe
        if (c + 1 < NC) {
            int nb_ = (c + 1) & 1;
#pragma unroll
            for (int j = 0; j < 4; j++) {
                int seg = w * 4 + j;
                const ushort* g = Bp + (size_t)(c + 1) * 8192 + (size_t)seg * 512;
                ushort* l = Bsm[nb_] + seg * 512;
                __builtin_amdgcn_global_load_lds(
                    (const __attribute__((address_space(1))) uint*)(g + (size_t)lane * 8),
                    (__attribute__((address_space(3))) uint*)l, 16, 0, 0);
            }
        }
        f16x8 fa[2], fb[4];
#pragma unroll
        for (int i = 0; i < 2; i++) {
            int off = c * 1024 + (i * 16 + l15) * 32 + quad * 8;
            fa[i] = *(const f16x8*)&Asm[off];
        }
#pragma unroll
        for (int j = 0; j < 4; j++) {
            int off = (w * 64 + j * 16 + l15) * 32 + quad * 8;
            fb[j] = *(const f16x8*)&Bsm[c & 1][off];
        }
#pragma unroll
        for (int i = 0; i < 2; i++)
#pragma unroll
            for (int j = 0; j < 4; j++)
                acc[i][j] = __builtin_amdgcn_mfma_f32_16x16x32_f16(fa[i], fb[j], acc[i][j], 0, 0, 0);
    }

    float bj[4];
#pragma unroll
    for (int j = 0; j < 4; j++) bj[j] = bias[w * 64 + j * 16 + l15];

    if constexpr (MODE == 1) {
#pragma unroll
        for (int i = 0; i < 2; i++)
#pragma unroll
            for (int reg = 0; reg < 4; reg++) {
                int r = row0 + i * 16 + quad * 4 + reg;
                if (r < M) {
                    ushort* cp = C16 + (size_t)r * 256 + w * 64 + l15;
#pragma unroll
                    for (int j = 0; j < 4; j++) {
                        float v = fmaxf(acc[i][j][reg] + bj[j], 0.f);
                        cp[j * 16] = __half_as_ushort(__float2half(v));
                    }
                }
            }
    } else {
        float wl0[4], wl1[4];
#pragma unroll
        for (int j = 0; j < 4; j++) {
            int cj = w * 64 + j * 16 + l15;
            float2 wv = *(const float2*)(Wl + cj * 2);
            wl0[j] = wv.x; wl1[j] = wv.y;
        }
#pragma unroll
        for (int i = 0; i < 2; i++)
#pragma unroll
            for (int reg = 0; reg < 4; reg++) {
                float s0 = 0.f, s1 = 0.f;
#pragma unroll
                for (int j = 0; j < 4; j++) {
                    float v = fmaxf(acc[i][j][reg] + bj[j], 0.f);
                    s0 += v * wl0[j];
                    s1 += v * wl1[j];
                }
#pragma unroll
                for (int off = 1; off < 16; off <<= 1) {
                    s0 += __shfl_xor(s0, off);
                    s1 += __shfl_xor(s1, off);
                }
                if (l15 == 0) {
                    int r = i * 16 + quad * 4 + reg;
                    part[w][r][0] = s0;
                    part[w][r][1] = s1;
                }
            }
        __syncthreads();
        if (tid < 64) {
            int r = tid >> 1, o = tid & 1;
            int grr = row0 + r;
            if (grr < M) {
                float s = part[0][r][o] + part[1][r][o] + part[2][r][o] + part[3][r][o] + bl[o];
                out[(size_t)grr * 2 + o] = s;
            }
        }
    }
}

// ---------------- launch ----------------

extern "C" void kernel_launch(void* const* d_in, const int* in_sizes, int n_in,
                              void* d_out, int out_size, void* d_ws, size_t ws_size,
                              hipStream_t stream) {
    const float* x  = (const float*)d_in[0];
    const int*   ei = (const int*)d_in[1];
    const float* W1 = (const float*)d_in[2];
    const float* b1 = (const float*)d_in[3];
    const float* W2 = (const float*)d_in[4];
    const float* b2 = (const float*)d_in[5];
    const float* Wl = (const float*)d_in[6];
    const float* bl = (const float*)d_in[7];
    float* out = (float*)d_out;

    int n = in_sizes[0] / IN_DIM;  // 50000
    int e = in_sizes[1] / 2;       // 600000
    const int* src = ei;
    const int* dst = ei + e;

    int gblocks = (n + 31) / 32;   // BM=32
    int Mp = gblocks * 32;

    char* ws = (char*)d_ws;
    size_t off = 0;
    auto alloc = [&](size_t bytes) -> void* {
        void* p = ws + off;
        off += (bytes + 255) & ~(size_t)255;
        return p;
    };
    int*    deg    = (int*)alloc((size_t)n * 4);
    int*    cursor = (int*)alloc((size_t)n * 4);
    float*  dinv   = (float*)alloc((size_t)n * 4);
    int*    rowptr = (int*)alloc((size_t)(n + 1) * 4);
    int*    escan  = (int*)alloc((size_t)n * 4);
    int*    bsum   = (int*)alloc(256 * 4);
    int*    ssrc   = (int*)alloc((size_t)e * 4);
    float*  ewt    = (float*)alloc((size_t)e * 4);
    ushort* xh     = (ushort*)alloc((size_t)n * IN_DIM * 2);
    ushort* h1     = (ushort*)alloc((size_t)n * HID * 2);
    ushort* A1p    = (ushort*)alloc((size_t)Mp * IN_DIM * 2);
    ushort* A2p    = (ushort*)alloc((size_t)Mp * HID * 2);
    ushort* B1p    = (ushort*)alloc((size_t)IN_DIM * 256 * 2);
    ushort* B2p    = (ushort*)alloc((size_t)HID * 256 * 2);

    int nb = (n + 255) / 256;   // 196 (<= 256 required by scan_rest)
    int eb = (e + 255) / 256;

    int total4 = n * IN_DIM / 4;
    int citems = IN_DIM * 64 + HID * 64 + total4 + n;
    convert_inputs<<<(citems + 255) / 256, 256, 0, stream>>>(W1, B1p, W2, B2p, x, xh,
                                                             total4, deg, cursor, n);

    count_deg<<<eb, 256, 0, stream>>>(dst, deg, e);
    scan_partial<<<nb, 256, 0, stream>>>(deg, escan, bsum, dinv, n);
    scan_rest<<<nb, 256, 0, stream>>>(escan, bsum, nb, rowptr, n);
    scatter_edges<<<eb, 256, 0, stream>>>(src, dst, rowptr, cursor, dinv, ssrc, ewt, e);

    // layer 1: aggregate fp16 x -> A1 panel, DMA-dbuf fp16-MFMA GEMM -> fp16 h1
    aggregate_p<IN_DIM><<<(n + 3) / 4, 256, 0, stream>>>(xh, rowptr, ssrc, ewt, dinv,
                                                         A1p, n, Mp);
    gemm_f16<IN_DIM, 1><<<gblocks, 256, 0, stream>>>(A1p, B1p, b1, h1,
                                                     nullptr, nullptr, nullptr, n, Mp);

    // layer 2: aggregate fp16 h1 -> A2 panel, DMA-dbuf GEMM + final projection
    aggregate_p<HID><<<(n + 3) / 4, 256, 0, stream>>>(h1, rowptr, ssrc, ewt, dinv,
                                                      A2p, n, Mp);
    gemm_f16<HID, 2><<<gblocks, 256, 0, stream>>>(A2p, B2p, b2, nullptr,
                                                  Wl, bl, out, n, Mp);
}

// Round 15
// 252.070 us; speedup vs baseline: 1.0240x; 1.0110x over previous
//
#include <hip/hip_runtime.h>
#include <hip/hip_bf16.h>
#include <hip/hip_fp16.h>

constexpr int IN_DIM = 128;
constexpr int HID    = 256;

typedef _Float16 f16x8 __attribute__((ext_vector_type(8)));
typedef float    f32x4 __attribute__((ext_vector_type(4)));

// ---------------- setup kernels ----------------

__global__ void count_deg(const int* __restrict__ dst, int* __restrict__ deg, int e) {
    int i = blockIdx.x * blockDim.x + threadIdx.x;
    if (i < e) atomicAdd(&deg[dst[i]], 1);
}

// ---- scan phase 1: per-block scan + block total; also emits dinv ----
__global__ __launch_bounds__(256) void scan_partial(const int* __restrict__ deg,
                                                    int* __restrict__ escan,
                                                    int* __restrict__ blocksum,
                                                    float* __restrict__ dinv, int n) {
    __shared__ int lds[256];
    int t = threadIdx.x;
    int i = blockIdx.x * 256 + t;
    int v = (i < n) ? deg[i] : 0;
    if (i < n) dinv[i] = rsqrtf((float)v + 1.0f);
    lds[t] = v;
    __syncthreads();
    for (int off = 1; off < 256; off <<= 1) {
        int a = lds[t];
        int w = (t >= off) ? lds[t - off] : 0;
        __syncthreads();
        lds[t] = a + w;
        __syncthreads();
    }
    if (i < n) escan[i] = lds[t] - v;
    if (t == 255) blocksum[blockIdx.x] = lds[255];
}

// ---- scan phases 2+3 fused ----
__global__ __launch_bounds__(256) void scan_rest(const int* __restrict__ escan,
                                                 const int* __restrict__ blocksum,
                                                 int nb, int* __restrict__ rowptr, int n) {
    __shared__ int lds[256];
    int t = threadIdx.x;
    int v = (t < nb) ? blocksum[t] : 0;
    lds[t] = v;
    __syncthreads();
    for (int off = 1; off < 256; off <<= 1) {
        int a = lds[t];
        int w = (t >= off) ? lds[t - off] : 0;
        __syncthreads();
        lds[t] = a + w;
        __syncthreads();
    }
    int boff = (blockIdx.x > 0) ? lds[blockIdx.x - 1] : 0;
    int i = blockIdx.x * 256 + t;
    if (i < n) rowptr[i] = escan[i] + boff;
    if (blockIdx.x == 0 && t == 0) rowptr[n] = lds[nb - 1];
}

// R14: single packed (src, weight) int2 write instead of two scattered 4B
// writes to different arrays — halves random write-line RMWs.
__global__ void scatter_edges(const int* __restrict__ src, const int* __restrict__ dst,
                              const int* __restrict__ rowptr, int* __restrict__ cursor,
                              const float* __restrict__ dinv,
                              int2* __restrict__ esw, int e) {
    int i = blockIdx.x * blockDim.x + threadIdx.x;
    if (i < e) {
        int d = dst[i];
        int s = src[i];
        int p = atomicAdd(&cursor[d], 1);
        esw[rowptr[d] + p] = make_int2(s, __float_as_int(dinv[s] * dinv[d]));
    }
}

// ---- fused: W1/W2 -> fp16 panels, x -> fp16, zero deg+cursor ----
__device__ inline void conv_B_elem(const float* B, ushort* Bp, int id) {
    int k  = id >> 6;
    int n4 = (id & 63) * 4;
    float4 v = *(const float4*)(B + (size_t)k * 256 + n4);
    size_t base = (size_t)(k >> 5) * (256 * 32) + (k & 31);
    Bp[base + (size_t)(n4 + 0) * 32] = __half_as_ushort(__float2half(v.x));
    Bp[base + (size_t)(n4 + 1) * 32] = __half_as_ushort(__float2half(v.y));
    Bp[base + (size_t)(n4 + 2) * 32] = __half_as_ushort(__float2half(v.z));
    Bp[base + (size_t)(n4 + 3) * 32] = __half_as_ushort(__float2half(v.w));
}

__global__ void convert_inputs(const float* __restrict__ W1, ushort* __restrict__ B1p,
                               const float* __restrict__ W2, ushort* __restrict__ B2p,
                               const float* __restrict__ x, ushort* __restrict__ xh,
                               int total4, int* __restrict__ deg,
                               int* __restrict__ cursor, int n) {
    int id = blockIdx.x * 256 + threadIdx.x;
    constexpr int C1 = IN_DIM * 64;
    constexpr int C2 = C1 + HID * 64;
    if (id < C1) {
        conv_B_elem(W1, B1p, id);
    } else if (id < C2) {
        conv_B_elem(W2, B2p, id - C1);
    } else if (id < C2 + total4) {
        int i = id - C2;
        float4 v = *(const float4*)(x + (size_t)i * 4);
        ushort4 o;
        o.x = __half_as_ushort(__float2half(v.x));
        o.y = __half_as_ushort(__float2half(v.y));
        o.z = __half_as_ushort(__float2half(v.z));
        o.w = __half_as_ushort(__float2half(v.w));
        *(ushort4*)(xh + (size_t)i * 4) = o;
    } else {
        int i = id - (C2 + total4);
        if (i < n) { deg[i] = 0; cursor[i] = 0; }
    }
}

// ---------------- aggregation: one wave per node, fp16 gather, 8-deep MLP --
// Edge stream is now packed int2 (src, weight) -> one uint2 load per edge.
template <int K>  // K halves per row: 128 or 256
__global__ __launch_bounds__(256) void aggregate_p(const ushort* __restrict__ h,
                                                   const int* __restrict__ rowptr,
                                                   const int2* __restrict__ esw,
                                                   const float* __restrict__ dinv,
                                                   ushort* __restrict__ Pp,
                                                   int n, int Mp) {
    constexpr int VH = K / 64;  // halves per lane: 2 or 4
    int wid  = (blockIdx.x * 256 + threadIdx.x) >> 6;
    int lane = threadIdx.x & 63;
    if (wid >= n) return;
    float di = dinv[wid];
    float sw = di * di;
    float acc[VH];
    {
        const ushort* row = h + (size_t)wid * K + lane * VH;
        if constexpr (VH == 4) {
            uint2 u = *(const uint2*)row;
            float2 fa = __half22float2(*(__half2*)&u.x);
            float2 fb = __half22float2(*(__half2*)&u.y);
            acc[0] = fa.x * sw; acc[1] = fa.y * sw; acc[2] = fb.x * sw; acc[3] = fb.y * sw;
        } else {
            uint u = *(const uint*)row;
            float2 fa = __half22float2(*(__half2*)&u);
            acc[0] = fa.x * sw; acc[1] = fa.y * sw;
        }
    }
    int beg = rowptr[wid], fin = rowptr[wid + 1];
    for (int b = beg; b < fin; b += 64) {
        int cnt = fin - b;
        if (cnt > 64) cnt = 64;
        int2 pk = (lane < cnt) ? esw[b + lane] : make_int2(0, 0);
        int   sv = pk.x;
        float wv = __int_as_float(pk.y);
        int t = 0;
        for (; t + 8 <= cnt; t += 8) {
            float wr[8];
            if constexpr (VH == 4) {
                uint2 u[8];
#pragma unroll
                for (int k = 0; k < 8; k++) {
                    int s = __shfl(sv, t + k);
                    wr[k] = __shfl(wv, t + k);
                    u[k] = *(const uint2*)(h + (size_t)s * K + lane * VH);
                }
#pragma unroll
                for (int k = 0; k < 8; k++) {
                    float2 fa = __half22float2(*(__half2*)&u[k].x);
                    float2 fb = __half22float2(*(__half2*)&u[k].y);
                    acc[0] += fa.x * wr[k]; acc[1] += fa.y * wr[k];
                    acc[2] += fb.x * wr[k]; acc[3] += fb.y * wr[k];
                }
            } else {
                uint u[8];
#pragma unroll
                for (int k = 0; k < 8; k++) {
                    int s = __shfl(sv, t + k);
                    wr[k] = __shfl(wv, t + k);
                    u[k] = *(const uint*)(h + (size_t)s * K + lane * VH);
                }
#pragma unroll
                for (int k = 0; k < 8; k++) {
                    float2 fa = __half22float2(*(__half2*)&u[k]);
                    acc[0] += fa.x * wr[k]; acc[1] += fa.y * wr[k];
                }
            }
        }
        for (; t + 4 <= cnt; t += 4) {
            float wr[4];
            if constexpr (VH == 4) {
                uint2 u[4];
#pragma unroll
                for (int k = 0; k < 4; k++) {
                    int s = __shfl(sv, t + k);
                    wr[k] = __shfl(wv, t + k);
                    u[k] = *(const uint2*)(h + (size_t)s * K + lane * VH);
                }
#pragma unroll
                for (int k = 0; k < 4; k++) {
                    float2 fa = __half22float2(*(__half2*)&u[k].x);
                    float2 fb = __half22float2(*(__half2*)&u[k].y);
                    acc[0] += fa.x * wr[k]; acc[1] += fa.y * wr[k];
                    acc[2] += fb.x * wr[k]; acc[3] += fb.y * wr[k];
                }
            } else {
                uint u[4];
#pragma unroll
                for (int k = 0; k < 4; k++) {
                    int s = __shfl(sv, t + k);
                    wr[k] = __shfl(wv, t + k);
                    u[k] = *(const uint*)(h + (size_t)s * K + lane * VH);
                }
#pragma unroll
                for (int k = 0; k < 4; k++) {
                    float2 fa = __half22float2(*(__half2*)&u[k]);
                    acc[0] += fa.x * wr[k]; acc[1] += fa.y * wr[k];
                }
            }
        }
        for (; t < cnt; t++) {
            int   s = __shfl(sv, t);
            float w = __shfl(wv, t);
            const ushort* r = h + (size_t)s * K + lane * VH;
            if constexpr (VH == 4) {
                uint2 u = *(const uint2*)r;
                float2 fa = __half22float2(*(__half2*)&u.x);
                float2 fb = __half22float2(*(__half2*)&u.y);
                acc[0] += fa.x * w; acc[1] += fa.y * w;
                acc[2] += fb.x * w; acc[3] += fb.y * w;
            } else {
                uint u = *(const uint*)r;
                float2 fa = __half22float2(*(__half2*)&u);
                acc[0] += fa.x * w; acc[1] += fa.y * w;
            }
        }
    }
    int kglob = lane * VH;
    int chunk = kglob >> 5;
    int inner = kglob & 31;
    size_t base = (size_t)chunk * Mp * 32 + (size_t)wid * 32 + inner;
    if constexpr (VH == 4) {
        __half2 p0 = __floats2half2_rn(acc[0], acc[1]);
        __half2 p1 = __floats2half2_rn(acc[2], acc[3]);
        *(uint2*)&Pp[base] = make_uint2(*(uint*)&p0, *(uint*)&p1);
    } else {
        __half2 p0 = __floats2half2_rn(acc[0], acc[1]);
        *(uint*)&Pp[base] = *(uint*)&p0;
    }
}

// ---------------- fp16 MFMA GEMM: A + B both via LDS-DMA (m97-style) -------
// MODE 1: C16[M,256] = fp16(relu(A@B + bias))
// MODE 2: out[M,2]  = relu(A@B + bias) @ Wl + bl
template <int K, int MODE>
__global__ __launch_bounds__(256, 3) void gemm_f16(const ushort* __restrict__ Ap,
                                                   const ushort* __restrict__ Bp,
                                                   const float* __restrict__ bias,
                                                   ushort* __restrict__ C16,
                                                   const float* __restrict__ Wl,
                                                   const float* __restrict__ bl,
                                                   float* __restrict__ out,
                                                   int M, int Mp) {
    constexpr int NC = K / 32;
    __shared__ ushort Asm[NC * 1024];   // A tile [chunk][row 0..31][32]
    __shared__ ushort Bsm[2][8192];     // B chunk dbuf (16 KB each)
    __shared__ float part[4][32][2];    // MODE 2 only

    int tid  = threadIdx.x;
    int w    = tid >> 6;
    int lane = tid & 63;
    int l15  = lane & 15;
    int quad = lane >> 4;
    int row0 = blockIdx.x * 32;

    constexpr int TOTA = NC * 2;
    for (int j = w; j < TOTA; j += 4) {
        int c   = j >> 1;
        int sub = j & 1;
        const ushort* g = Ap + (size_t)c * Mp * 32 + (size_t)(row0 + sub * 16) * 32;
        ushort* l = Asm + c * 1024 + sub * 512;
        __builtin_amdgcn_global_load_lds(
            (const __attribute__((address_space(1))) uint*)(g + (size_t)lane * 8),
            (__attribute__((address_space(3))) uint*)l, 16, 0, 0);
    }
#pragma unroll
    for (int j = 0; j < 4; j++) {
        int seg = w * 4 + j;
        const ushort* g = Bp + (size_t)seg * 512;
        ushort* l = Bsm[0] + seg * 512;
        __builtin_amdgcn_global_load_lds(
            (const __attribute__((address_space(1))) uint*)(g + (size_t)lane * 8),
            (__attribute__((address_space(3))) uint*)l, 16, 0, 0);
    }

    f32x4 acc[2][4] = {};
#pragma unroll
    for (int c = 0; c < NC; c++) {
        __syncthreads();
        if (c + 1 < NC) {
            int nb_ = (c + 1) & 1;
#pragma unroll
            for (int j = 0; j < 4; j++) {
                int seg = w * 4 + j;
                const ushort* g = Bp + (size_t)(c + 1) * 8192 + (size_t)seg * 512;
                ushort* l = Bsm[nb_] + seg * 512;
                __builtin_amdgcn_global_load_lds(
                    (const __attribute__((address_space(1))) uint*)(g + (size_t)lane * 8),
                    (__attribute__((address_space(3))) uint*)l, 16, 0, 0);
            }
        }
        f16x8 fa[2], fb[4];
#pragma unroll
        for (int i = 0; i < 2; i++) {
            int off = c * 1024 + (i * 16 + l15) * 32 + quad * 8;
            fa[i] = *(const f16x8*)&Asm[off];
        }
#pragma unroll
        for (int j = 0; j < 4; j++) {
            int off = (w * 64 + j * 16 + l15) * 32 + quad * 8;
            fb[j] = *(const f16x8*)&Bsm[c & 1][off];
        }
#pragma unroll
        for (int i = 0; i < 2; i++)
#pragma unroll
            for (int j = 0; j < 4; j++)
                acc[i][j] = __builtin_amdgcn_mfma_f32_16x16x32_f16(fa[i], fb[j], acc[i][j], 0, 0, 0);
    }

    float bj[4];
#pragma unroll
    for (int j = 0; j < 4; j++) bj[j] = bias[w * 64 + j * 16 + l15];

    if constexpr (MODE == 1) {
#pragma unroll
        for (int i = 0; i < 2; i++)
#pragma unroll
            for (int reg = 0; reg < 4; reg++) {
                int r = row0 + i * 16 + quad * 4 + reg;
                if (r < M) {
                    ushort* cp = C16 + (size_t)r * 256 + w * 64 + l15;
#pragma unroll
                    for (int j = 0; j < 4; j++) {
                        float v = fmaxf(acc[i][j][reg] + bj[j], 0.f);
                        cp[j * 16] = __half_as_ushort(__float2half(v));
                    }
                }
            }
    } else {
        float wl0[4], wl1[4];
#pragma unroll
        for (int j = 0; j < 4; j++) {
            int cj = w * 64 + j * 16 + l15;
            float2 wv = *(const float2*)(Wl + cj * 2);
            wl0[j] = wv.x; wl1[j] = wv.y;
        }
#pragma unroll
        for (int i = 0; i < 2; i++)
#pragma unroll
            for (int reg = 0; reg < 4; reg++) {
                float s0 = 0.f, s1 = 0.f;
#pragma unroll
                for (int j = 0; j < 4; j++) {
                    float v = fmaxf(acc[i][j][reg] + bj[j], 0.f);
                    s0 += v * wl0[j];
                    s1 += v * wl1[j];
                }
#pragma unroll
                for (int off = 1; off < 16; off <<= 1) {
                    s0 += __shfl_xor(s0, off);
                    s1 += __shfl_xor(s1, off);
                }
                if (l15 == 0) {
                    int r = i * 16 + quad * 4 + reg;
                    part[w][r][0] = s0;
                    part[w][r][1] = s1;
                }
            }
        __syncthreads();
        if (tid < 64) {
            int r = tid >> 1, o = tid & 1;
            int grr = row0 + r;
            if (grr < M) {
                float s = part[0][r][o] + part[1][r][o] + part[2][r][o] + part[3][r][o] + bl[o];
                out[(size_t)grr * 2 + o] = s;
            }
        }
    }
}

// ---------------- launch ----------------

extern "C" void kernel_launch(void* const* d_in, const int* in_sizes, int n_in,
                              void* d_out, int out_size, void* d_ws, size_t ws_size,
                              hipStream_t stream) {
    const float* x  = (const float*)d_in[0];
    const int*   ei = (const int*)d_in[1];
    const float* W1 = (const float*)d_in[2];
    const float* b1 = (const float*)d_in[3];
    const float* W2 = (const float*)d_in[4];
    const float* b2 = (const float*)d_in[5];
    const float* Wl = (const float*)d_in[6];
    const float* bl = (const float*)d_in[7];
    float* out = (float*)d_out;

    int n = in_sizes[0] / IN_DIM;  // 50000
    int e = in_sizes[1] / 2;       // 600000
    const int* src = ei;
    const int* dst = ei + e;

    int gblocks = (n + 31) / 32;   // BM=32
    int Mp = gblocks * 32;

    char* ws = (char*)d_ws;
    size_t off = 0;
    auto alloc = [&](size_t bytes) -> void* {
        void* p = ws + off;
        off += (bytes + 255) & ~(size_t)255;
        return p;
    };
    int*    deg    = (int*)alloc((size_t)n * 4);
    int*    cursor = (int*)alloc((size_t)n * 4);
    float*  dinv   = (float*)alloc((size_t)n * 4);
    int*    rowptr = (int*)alloc((size_t)(n + 1) * 4);
    int*    escan  = (int*)alloc((size_t)n * 4);
    int*    bsum   = (int*)alloc(256 * 4);
    int2*   esw    = (int2*)alloc((size_t)e * 8);
    ushort* xh     = (ushort*)alloc((size_t)n * IN_DIM * 2);
    ushort* h1     = (ushort*)alloc((size_t)n * HID * 2);
    ushort* A1p    = (ushort*)alloc((size_t)Mp * IN_DIM * 2);
    ushort* A2p    = (ushort*)alloc((size_t)Mp * HID * 2);
    ushort* B1p    = (ushort*)alloc((size_t)IN_DIM * 256 * 2);
    ushort* B2p    = (ushort*)alloc((size_t)HID * 256 * 2);

    int nb = (n + 255) / 256;   // 196 (<= 256 required by scan_rest)
    int eb = (e + 255) / 256;

    int total4 = n * IN_DIM / 4;
    int citems = IN_DIM * 64 + HID * 64 + total4 + n;
    convert_inputs<<<(citems + 255) / 256, 256, 0, stream>>>(W1, B1p, W2, B2p, x, xh,
                                                             total4, deg, cursor, n);

    count_deg<<<eb, 256, 0, stream>>>(dst, deg, e);
    scan_partial<<<nb, 256, 0, stream>>>(deg, escan, bsum, dinv, n);
    scan_rest<<<nb, 256, 0, stream>>>(escan, bsum, nb, rowptr, n);
    scatter_edges<<<eb, 256, 0, stream>>>(src, dst, rowptr, cursor, dinv, esw, e);

    // layer 1: aggregate fp16 x -> A1 panel, DMA-dbuf fp16-MFMA GEMM -> fp16 h1
    aggregate_p<IN_DIM><<<(n + 3) / 4, 256, 0, stream>>>(xh, rowptr, esw, dinv,
                                                         A1p, n, Mp);
    gemm_f16<IN_DIM, 1><<<gblocks, 256, 0, stream>>>(A1p, B1p, b1, h1,
                                                     nullptr, nullptr, nullptr, n, Mp);

    // layer 2: aggregate fp16 h1 -> A2 panel, DMA-dbuf GEMM + final projection
    aggregate_p<HID><<<(n + 3) / 4, 256, 0, stream>>>(h1, rowptr, esw, dinv,
                                                      A2p, n, Mp);
    gemm_f16<HID, 2><<<gblocks, 256, 0, stream>>>(A2p, B2p, b2, nullptr,
                                                  Wl, bl, out, n, Mp);
}